// Round 22
// baseline (188.189 us; speedup 1.0000x reference)
//
#include <hip/hip_runtime.h>

typedef __attribute__((ext_vector_type(8))) _Float16 f16x8;
typedef __attribute__((ext_vector_type(4))) float f32x4;

#define S4 0.35355339059327373f   /* 64^-0.25 */

static __device__ __forceinline__ ushort f2h(float f) {
  return __builtin_bit_cast(ushort, (_Float16)f);
}

static __device__ __forceinline__ void gload16(const void* g, void* l) {
  __builtin_amdgcn_global_load_lds((const __attribute__((address_space(1))) void*)g,
                                   (__attribute__((address_space(3))) void*)l, 16, 0, 0);
}

static __device__ __forceinline__ f16x8 cvt8(float4 a, float4 b) {
  f16x8 h;
  h[0] = (_Float16)a.x; h[1] = (_Float16)a.y; h[2] = (_Float16)a.z; h[3] = (_Float16)a.w;
  h[4] = (_Float16)b.x; h[5] = (_Float16)b.y; h[6] = (_Float16)b.z; h[7] = (_Float16)b.w;
  return h;
}

// ---------------------------------------------------------------------------
// Generic C[M,N] = A[M,K] @ B[N,K]^T (+ epilogue), fp16 MFMA, fp32 accum.
// EPI 3: +bias[col] -> fp32        (out projection)
// EPI 5: raw fp32 store            (ctx split-K partials)
// EPI 6: 0.0625*exp(acc - rv[col]) + 1e-4 -> fp16 (phi K^T, col-diag)
// ZMODE 0/2/3 as before.
// ---------------------------------------------------------------------------
template<int BM, int BN, int WR, int WC, int EPI, int ZMODE>
__global__ __launch_bounds__(256) void gemm_bt(
    const ushort* __restrict__ Ah, const ushort* __restrict__ Bh,
    const float* __restrict__ bias, ushort* __restrict__ Cb,
    float* __restrict__ Cf, const float* __restrict__ rv0,
    int K, int ldA, int ldB, int ldC, int Mz,
    long sAz, long sBz, long sCz)
{
  constexpr int BK = 32;
  constexpr int WTM = BM / WR, WTN = BN / WC;
  constexpr int MI = WTM / 16, NI = WTN / 16;
  constexpr int LDSB = (BM + BN) * 64;

  __shared__ uint4 smem4[LDSB / 16];
  char* smem = (char*)smem4;
  ushort* As = (ushort*)smem;                 // [BM][32]
  ushort* Bs = (ushort*)(smem + BM * 64);     // [BN][32]

  const int tid = threadIdx.x;
  const int l = tid & 63, w = tid >> 6;
  const int wr = w / WC, wc = w % WC;
  const int lr = l & 15, lk = l >> 4;
  const int tm = blockIdx.x * BM, tn = blockIdx.y * BN;
  const int z = blockIdx.z;

  long aoff = 0, boff = 0;
  if (ZMODE == 0) { aoff = (long)z * sAz; boff = (long)z * sBz; }
  if (ZMODE == 2) { aoff = (long)z * sAz; boff = (long)(z >> 3) * sBz + (z & 7) * 64; }
  if (ZMODE == 3) {
    aoff = (long)(z & 15) * sAz + (long)(z >> 4) * 1024;
    boff = (long)(z & 15) * sBz + (long)(z >> 4) * 1024;
  }
  Ah += aoff; Bh += boff;
  const float* rv = (EPI == 6) ? (rv0 + (long)z * Mz) : nullptr;
  const long coff = (long)z * sCz;

  f32x4 acc[MI][NI];
#pragma unroll
  for (int i = 0; i < MI; ++i)
#pragma unroll
    for (int j = 0; j < NI; ++j) acc[i][j] = f32x4{0.f, 0.f, 0.f, 0.f};

  for (int k0 = 0; k0 < K; k0 += BK) {
    constexpr int AB = BM * 64;
#pragma unroll
    for (int s = 0; s < (AB + 4095) / 4096; ++s) {
      const int base = s * 4096 + w * 1024;
      if (base < AB) {
        const int idx = base + l * 16;
        gload16(Ah + (long)(tm + (idx >> 6)) * ldA + k0 + ((idx & 63) >> 1),
                (char*)As + base);
      }
    }
    constexpr int BB = BN * 64;
#pragma unroll
    for (int s = 0; s < (BB + 4095) / 4096; ++s) {
      const int base = s * 4096 + w * 1024;
      if (base < BB) {
        const int idx = base + l * 16;
        gload16(Bh + (long)(tn + (idx >> 6)) * ldB + k0 + ((idx & 63) >> 1),
                (char*)Bs + base);
      }
    }
    __syncthreads();

    f16x8 af[MI], bfr[NI];
#pragma unroll
    for (int mi = 0; mi < MI; ++mi)
      af[mi] = *(const f16x8*)(As + (wr * WTM + mi * 16 + lr) * 32 + lk * 8);
#pragma unroll
    for (int ni = 0; ni < NI; ++ni)
      bfr[ni] = *(const f16x8*)(Bs + (wc * WTN + ni * 16 + lr) * 32 + lk * 8);
#pragma unroll
    for (int mi = 0; mi < MI; ++mi)
#pragma unroll
      for (int ni = 0; ni < NI; ++ni)
        acc[mi][ni] = __builtin_amdgcn_mfma_f32_16x16x32_f16(af[mi], bfr[ni], acc[mi][ni], 0, 0, 0);
    __syncthreads();
  }

#pragma unroll
  for (int mi = 0; mi < MI; ++mi) {
#pragma unroll
    for (int j = 0; j < 4; ++j) {
      const int row = tm + wr * WTM + mi * 16 + lk * 4 + j;
#pragma unroll
      for (int ni = 0; ni < NI; ++ni) {
        const int col = tn + wc * WTN + ni * 16 + lr;
        float v = acc[mi][ni][j];
        if (EPI == 3) v += bias[col];
        if (EPI == 6) v = 0.0625f * __expf(v - rv[col]) + 1e-4f;
        if (EPI == 3 || EPI == 5) {
          Cf[coff + (long)row * ldC + col] = v;
        } else {
          Cb[coff + (long)row * ldC + col] = f2h(v);
        }
      }
    }
  }
}

// ---------------------------------------------------------------------------
// frontend_k: merged Q-proj + K-proj + V^T-proj in ONE launch. grid (128,1,12):
//   z<8:  qkproj path (z&1 = q/k, z>>1 = 128-col block; dbuf fp32 staging)
//   z>=8: vproj path (z-8 = WV row block, bx = v row block; BF32 staging)
// 48 KB LDS -> 3 blocks/CU.
// ---------------------------------------------------------------------------
__global__ __launch_bounds__(256) void frontend_k(
    const float* __restrict__ qf, const float* __restrict__ kf,
    const float* __restrict__ vf,
    const ushort* __restrict__ wqh, const ushort* __restrict__ wkh,
    const ushort* __restrict__ wvh,
    const float* __restrict__ bq, const float* __restrict__ bk,
    const float* __restrict__ bv,
    ushort* __restrict__ Qh, ushort* __restrict__ Kh,
    ushort* __restrict__ Vt,
    float* __restrict__ diagQ, float* __restrict__ diagK)
{
  __shared__ uint4 smem4[3072];   // 49152 B
  char* smem = (char*)smem4;
  const int tid = threadIdx.x;
  const int l = tid & 63, w = tid >> 6;
  const int wr = w >> 1, wc = w & 1;
  const int lr = l & 15, lk = l >> 4;
  const int z = blockIdx.z;

  if (z < 8) {
    const int qk = z & 1;
    const float*  Af   = qk ? kf : qf;
    const ushort* Bh   = qk ? wkh : wqh;
    const float*  bias = qk ? bk : bq;
    ushort*       Cb   = qk ? Kh : Qh;
    float*        dg   = qk ? diagK : diagQ;
    const int tm = blockIdx.x * 128;
    const int tn = (z >> 1) * 128;

    char* AsF[2] = { smem, smem + 16384 };
    char* Bsb[2] = { smem + 32768, smem + 40960 };
    const int baseA = w * 1024;

    f32x4 acc[4][4];
#pragma unroll
    for (int i = 0; i < 4; ++i)
#pragma unroll
      for (int j = 0; j < 4; ++j) acc[i][j] = f32x4{0.f, 0.f, 0.f, 0.f};

#pragma unroll
    for (int s = 0; s < 4; ++s) {
      const int base = s * 4096 + baseA;
      const int D = base + l * 16;
      const int m = D >> 7, pos = (D >> 4) & 7;
      const int g = pos ^ (m & 7);
      gload16(Af + (long)(tm + m) * 512 + g * 4, AsF[0] + base);
    }
#pragma unroll
    for (int s = 0; s < 2; ++s) {
      const int base = s * 4096 + baseA;
      const int D = base + l * 16;
      const int m = D >> 6, pos = (D >> 4) & 3;
      const int g = pos ^ (m & 3);
      gload16(Bh + (long)(tn + m) * 512 + g * 8, Bsb[0] + base);
    }
    __syncthreads();

#pragma unroll
    for (int t = 0; t < 16; ++t) {
      const int cur = t & 1, nxt = cur ^ 1;
      if (t < 15) {
        const int kn = (t + 1) * 32;
#pragma unroll
        for (int s = 0; s < 4; ++s) {
          const int base = s * 4096 + baseA;
          const int D = base + l * 16;
          const int m = D >> 7, pos = (D >> 4) & 7;
          const int g = pos ^ (m & 7);
          gload16(Af + (long)(tm + m) * 512 + kn + g * 4, AsF[nxt] + base);
        }
#pragma unroll
        for (int s = 0; s < 2; ++s) {
          const int base = s * 4096 + baseA;
          const int D = base + l * 16;
          const int m = D >> 6, pos = (D >> 4) & 3;
          const int g = pos ^ (m & 3);
          gload16(Bh + (long)(tn + m) * 512 + kn + g * 8, Bsb[nxt] + base);
        }
      }

      f16x8 af[4], bfr[4];
#pragma unroll
      for (int mi = 0; mi < 4; ++mi) {
        const int row = wr * 64 + mi * 16 + lr;
        const char* rb = AsF[cur] + row * 128;
        float4 f0 = *(const float4*)(rb + ((((lk << 1) | 0) ^ (row & 7)) << 4));
        float4 f1 = *(const float4*)(rb + ((((lk << 1) | 1) ^ (row & 7)) << 4));
        af[mi] = cvt8(f0, f1);
      }
#pragma unroll
      for (int ni = 0; ni < 4; ++ni) {
        const int row = wc * 64 + ni * 16 + lr;
        const int pb = (lk ^ (row & 3)) << 4;
        bfr[ni] = *(const f16x8*)(Bsb[cur] + row * 64 + pb);
      }
#pragma unroll
      for (int mi = 0; mi < 4; ++mi)
#pragma unroll
        for (int ni = 0; ni < 4; ++ni)
          acc[mi][ni] = __builtin_amdgcn_mfma_f32_16x16x32_f16(af[mi], bfr[ni], acc[mi][ni], 0, 0, 0);
      __syncthreads();
    }

#pragma unroll
    for (int mi = 0; mi < 4; ++mi) {
#pragma unroll
      for (int j = 0; j < 4; ++j) {
        const int row = tm + wr * 64 + mi * 16 + lk * 4 + j;
        float ds = 0.f;
#pragma unroll
        for (int ni = 0; ni < 4; ++ni) {
          const int col = tn + wc * 64 + ni * 16 + lr;
          float v = acc[mi][ni][j] + bias[col];
          ds += v * v;
          Cb[(long)row * 512 + col] = f2h(v);
        }
        ds += __shfl_xor(ds, 1, 64);
        ds += __shfl_xor(ds, 2, 64);
        ds += __shfl_xor(ds, 4, 64);
        ds += __shfl_xor(ds, 8, 64);
        if (lr == 0) {
          const int b = row >> 13, nn = row & 8191;
          const int head = (tn + wc * 64) >> 6;
          dg[(long)(b * 8 + head) * 8192 + nn] = 0.0625f * ds;
        }
      }
    }
  } else {
    const int tm = (z - 8) * 128;
    const int tn = blockIdx.x * 128;
    ushort* As = (ushort*)smem;
    char*   Bb = smem + 8192;

    f32x4 acc[4][4];
#pragma unroll
    for (int i = 0; i < 4; ++i)
#pragma unroll
      for (int j = 0; j < 4; ++j) acc[i][j] = f32x4{0.f, 0.f, 0.f, 0.f};

    for (int k0 = 0; k0 < 512; k0 += 32) {
#pragma unroll
      for (int s = 0; s < 2; ++s) {
        const int base = s * 4096 + w * 1024;
        const int idx = base + l * 16;
        gload16(wvh + (long)(tm + (idx >> 6)) * 512 + k0 + ((idx & 63) >> 1),
                (char*)As + base);
      }
#pragma unroll
      for (int s = 0; s < 4; ++s) {
        const int base = s * 4096 + w * 1024;
        const int D = base + l * 16;
        const int m = D >> 7, slot = (D >> 4) & 7;
        const int g = slot ^ (m & 7);
        gload16(vf + (long)(tn + m) * 512 + k0 + g * 4, Bb + base);
      }
      __syncthreads();

      f16x8 af[4], bfr[4];
#pragma unroll
      for (int mi = 0; mi < 4; ++mi)
        af[mi] = *(const f16x8*)(As + (wr * 64 + mi * 16 + lr) * 32 + lk * 8);
#pragma unroll
      for (int ni = 0; ni < 4; ++ni) {
        const int row = wc * 64 + ni * 16 + lr;
        const char* rb = Bb + row * 128;
        float4 f0 = *(const float4*)(rb + ((((lk << 1) | 0) ^ (row & 7)) << 4));
        float4 f1 = *(const float4*)(rb + ((((lk << 1) | 1) ^ (row & 7)) << 4));
        bfr[ni] = cvt8(f0, f1);
      }
#pragma unroll
      for (int mi = 0; mi < 4; ++mi)
#pragma unroll
        for (int ni = 0; ni < 4; ++ni)
          acc[mi][ni] = __builtin_amdgcn_mfma_f32_16x16x32_f16(af[mi], bfr[ni], acc[mi][ni], 0, 0, 0);
      __syncthreads();
    }

#pragma unroll
    for (int mi = 0; mi < 4; ++mi) {
#pragma unroll
      for (int j = 0; j < 4; ++j) {
        const int row = tm + wr * 64 + mi * 16 + lk * 4 + j;
#pragma unroll
        for (int ni = 0; ni < 4; ++ni) {
          const int col = tn + wc * 64 + ni * 16 + lr;
          const float v = acc[mi][ni][j] + bv[row];
          const int b = col >> 13, nn = col & 8191;
          const int h = row >> 6, d = row & 63;
          Vt[(long)(b * 8 + h) * 655360 + (long)d * 8192 + nn] = f2h(v);
        }
      }
    }
  }
}

// ---------------------------------------------------------------------------
// phiattn_k v4: fused phi(Q)+attn(+denom), 64-row blocks, all-LDS MFMA
// operands, T14 async-STAGE: Cs global loads issued at entry (regs), written
// to LDS after phi. 79.9 KB LDS -> 2 blocks/CU. grid (bx<128, bh<16).
// ---------------------------------------------------------------------------
__global__ __launch_bounds__(256) void phiattn_k(
    const ushort* __restrict__ Qh, const ushort* __restrict__ pjh,
    const float* __restrict__ diagQ, const ushort* __restrict__ ctxb,
    ushort* __restrict__ attnR)
{
  const int bx = blockIdx.x, bh = blockIdx.y;
  const int b = bh >> 3, h = bh & 7;
  const int tm = bx * 64;
  const int tid = threadIdx.x, l = tid & 63, w = tid >> 6;
  const int lr = l & 15, lk = l >> 4;

  __shared__ uint4 smem4[4992];   // 79872 B
  char* smem = (char*)smem4;
  ushort* P  = (ushort*)smem;              // [64][264]
  ushort* Pj = (ushort*)(smem + 33792);    // [256][72]
  ushort* As = (ushort*)(smem + 70656);    // [64][72]
  ushort* Cs = (ushort*)(smem + 33792);    // [80][264] (overlays Pj/As)

  const ushort* QB = Qh + (long)b * 4194304 + h * 64;
  const float* rv = diagQ + (long)bh * 8192;

  // ---- T14: issue Cs loads into registers FIRST (latency hides under phi) ----
  const ushort* cb = ctxb + (long)bh * 20480;
  uint4 creg[10];
#pragma unroll
  for (int it = 0; it < 10; ++it) {
    const int g = it * 256 + tid;
    const int row = g >> 5, colg = (g & 31) * 8;
    creg[it] = *(const uint4*)(cb + row * 256 + colg);
  }

#pragma unroll
  for (int it = 0; it < 8; ++it) {
    const int g = it * 256 + tid;
    const int row = g >> 3, colg = (g & 7) * 8;
    *(uint4*)(Pj + row * 72 + colg) = *(const uint4*)(pjh + row * 64 + colg);
  }
#pragma unroll
  for (int it = 0; it < 2; ++it) {
    const int g = it * 256 + tid;
    const int row = g >> 3, colg = (g & 7) * 8;
    *(uint4*)(As + row * 72 + colg) = *(const uint4*)(QB + (long)(tm + row) * 512 + colg);
  }
  __syncthreads();

  f32x4 a2[16];
#pragma unroll
  for (int i = 0; i < 16; ++i) a2[i] = f32x4{0.f, 0.f, 0.f, 0.f};
  {
    f16x8 af0 = *(const f16x8*)(As + (w * 16 + lr) * 72 + lk * 8);
    f16x8 af1 = *(const f16x8*)(As + (w * 16 + lr) * 72 + 32 + lk * 8);
#pragma unroll
    for (int ni = 0; ni < 16; ++ni) {
      f16x8 b0 = *(const f16x8*)(Pj + (ni * 16 + lr) * 72 + lk * 8);
      f16x8 b1 = *(const f16x8*)(Pj + (ni * 16 + lr) * 72 + 32 + lk * 8);
      a2[ni] = __builtin_amdgcn_mfma_f32_16x16x32_f16(af0, b0, a2[ni], 0, 0, 0);
      a2[ni] = __builtin_amdgcn_mfma_f32_16x16x32_f16(af1, b1, a2[ni], 0, 0, 0);
    }
  }
#pragma unroll
  for (int ni = 0; ni < 16; ++ni)
#pragma unroll
    for (int j = 0; j < 4; ++j) {
      const int row = w * 16 + lk * 4 + j;
      const int col = ni * 16 + lr;
      const float vv = 0.0625f * __expf(a2[ni][j] - rv[tm + row]) + 1e-4f;
      P[row * 264 + col] = f2h(vv);
    }
  __syncthreads();   // Pj/As reads done

  // ---- write Cs from registers (loads completed long ago) ----
#pragma unroll
  for (int it = 0; it < 10; ++it) {
    const int g = it * 256 + tid;
    const int row = g >> 5, colg = (g & 31) * 8;
    *(uint4*)(Cs + row * 264 + colg) = creg[it];
  }
  __syncthreads();

  f32x4 acc[5];
#pragma unroll
  for (int i = 0; i < 5; ++i) acc[i] = f32x4{0.f, 0.f, 0.f, 0.f};

  for (int k0 = 0; k0 < 256; k0 += 32) {
    f16x8 pa = *(const f16x8*)(P + (w * 16 + lr) * 264 + k0 + lk * 8);
#pragma unroll
    for (int ni = 0; ni < 5; ++ni) {
      f16x8 cf = *(const f16x8*)(Cs + (ni * 16 + lr) * 264 + k0 + lk * 8);
      acc[ni] = __builtin_amdgcn_mfma_f32_16x16x32_f16(pa, cf, acc[ni], 0, 0, 0);
    }
  }

  ushort* outb = attnR + (long)bh * 524288;
#pragma unroll
  for (int j = 0; j < 4; ++j) {
    const float dv = __shfl(acc[4][j], (l & 48), 64);
    const int row = tm + w * 16 + lk * 4 + j;
#pragma unroll
    for (int ni = 0; ni < 4; ++ni) {
      const int col = ni * 16 + lr;
      outb[(long)row * 64 + col] = f2h(acc[ni][j] / dv);
    }
  }
}

// fp32->fp16 weight conversions (wq,wk,wv,wo,pj*S4) + Vt pad rows
__global__ __launch_bounds__(256) void cvtall_k(
    const float* __restrict__ wq, const float* __restrict__ wk,
    const float* __restrict__ wv, const float* __restrict__ wo,
    const float* __restrict__ pj,
    ushort* __restrict__ wqh, ushort* __restrict__ wkh,
    ushort* __restrict__ wvh, ushort* __restrict__ woh,
    ushort* __restrict__ pjh, ushort* __restrict__ Vt)
{
  int i = blockIdx.x * 256 + threadIdx.x;
  if (i >= 266240) {
    const int j = i - 266240;
    if (j >= 262144) return;
    const int bh = j >> 14, rem = j & 16383, r = rem >> 10, n8 = rem & 1023;
    const unsigned val = (r == 0) ? 0x3C003C00u : 0u;
    uint4 u; u.x = val; u.y = val; u.z = val; u.w = val;
    *(uint4*)(Vt + (long)bh * 655360 + (long)(64 + r) * 8192 + n8 * 8) = u;
    return;
  }
  const float* in; ushort* out; float scale = 1.f; int idx;
  if (i < 65536)       { in = wq; out = wqh; idx = i; }
  else if (i < 131072) { in = wk; out = wkh; idx = i - 65536; }
  else if (i < 196608) { in = wv; out = wvh; idx = i - 131072; }
  else if (i < 262144) { in = wo; out = woh; idx = i - 196608; }
  else                 { in = pj; out = pjh; idx = i - 262144; scale = S4; }
  float4 f = ((const float4*)in)[idx];
  ushort4 o;
  o.x = f2h(f.x * scale); o.y = f2h(f.y * scale);
  o.z = f2h(f.z * scale); o.w = f2h(f.w * scale);
  ((ushort4*)out)[idx] = o;
}

// reduce 8 ctx split-K partials -> fp16 ctxb[bh][80][256] (row 64 = ksum)
__global__ __launch_bounds__(256) void ctxred_k(const float* __restrict__ cp,
                                                ushort* __restrict__ ctxb) {
  const int idx = blockIdx.x * 256 + threadIdx.x;   // 327680
  const int bh = idx / 20480, rem = idx % 20480;
  float a = 0.f;
#pragma unroll
  for (int kc = 0; kc < 8; ++kc) a += cp[(long)(kc * 16 + bh) * 20480 + rem];
  ctxb[idx] = f2h(a);
}

extern "C" void kernel_launch(void* const* d_in, const int* in_sizes, int n_in,
                              void* d_out, int out_size, void* d_ws, size_t ws_size,
                              hipStream_t stream) {
  (void)in_sizes; (void)n_in; (void)out_size; (void)ws_size;
  const float* q  = (const float*)d_in[0];
  const float* k  = (const float*)d_in[1];
  const float* v  = (const float*)d_in[2];
  const float* wq = (const float*)d_in[3];
  const float* bq = (const float*)d_in[4];
  const float* wk = (const float*)d_in[5];
  const float* bk = (const float*)d_in[6];
  const float* wv = (const float*)d_in[7];
  const float* bv = (const float*)d_in[8];
  const float* wo = (const float*)d_in[9];
  const float* bo = (const float*)d_in[10];
  const float* pj = (const float*)d_in[11];

  char* ws = (char*)d_ws;
  ushort* attnR = (ushort*)(ws + 0);          // [16][8192][64]
  float*  cpart = (float*)(ws + 16777216);    // [128][80][256] fp32
  ushort* wqh   = (ushort*)(ws + 27262976);
  ushort* wkh   = (ushort*)(ws + 27787264);
  ushort* wvh   = (ushort*)(ws + 28311552);
  ushort* woh   = (ushort*)(ws + 28835840);
  ushort* pjh   = (ushort*)(ws + 29360128);
  ushort* Qh    = (ushort*)(ws + 29392896);   // [16384][512]
  ushort* Kh    = (ushort*)(ws + 46170112);   // [16384][512]
  ushort* Vt    = (ushort*)(ws + 62947328);   // [16][80][8192] (row64=1s)
  ushort* KpT   = (ushort*)(ws + 83918848);   // [16][256][8192]
  float*  diagQ = (float*)(ws + 151027712);
  float*  diagK = (float*)(ws + 151552000);
  ushort* ctxb  = (ushort*)(ws + 152076288);  // [16][80][256] (row64=ksum)

  // 1. weight conversions + Vt pad (small, single launch)
  cvtall_k<<<2064, 256, 0, stream>>>(wq, wk, wv, wo, pj, wqh, wkh, wvh, woh, pjh, Vt);

  // 2. merged front end: Q-proj + K-proj + V^T-proj in one launch
  frontend_k<<<dim3(128,1,12), 256, 0, stream>>>(
      q, k, v, wqh, wkh, wvh, bq, bk, bv, Qh, Kh, Vt, diagQ, diagK);

  // 3. phi(K)^T: C[m=256][n=8192] per bh -> KpT (col-diag exp epilogue)
  gemm_bt<128,128,2,2,6,2><<<dim3(2,64,16), 256, 0, stream>>>(
      pjh, Kh, nullptr, KpT, nullptr, diagK, 64, 64, 512, 8192, 8192,
      0L, 4194304L, 2097152L);

  // 4. ctx (+ksum via ones row): C[80][m=256] = Vt @ KpT^T, split-K x8,
  //    BN=64 -> 512 blocks (2/CU)
  gemm_bt<80,64,1,4,5,3><<<dim3(1,4,128), 256, 0, stream>>>(
      Vt, KpT, nullptr, nullptr, cpart, nullptr, 1024, 8192, 8192, 256, 0,
      655360L, 2097152L, 20480L);
  ctxred_k<<<1280, 256, 0, stream>>>(cpart, ctxb);

  // 5. fused phi(Q)+attn(+denom) v4 (T14 async Cs) -> attnR
  phiattn_k<<<dim3(128,16), 256, 0, stream>>>(Qh, pjh, diagQ, ctxb, attnR);

  // 6. output projection (+bias) -> fp32 d_out
  gemm_bt<128,128,2,2,3,0><<<dim3(128,4,1), 256, 0, stream>>>(
      attnR, woh, bo, nullptr, (float*)d_out, nullptr, 512, 512, 512, 512, 0,
      0L, 0L, 0L);
}

// Round 23
// 170.012 us; speedup vs baseline: 1.1069x; 1.1069x over previous
//
#include <hip/hip_runtime.h>

typedef __attribute__((ext_vector_type(8))) _Float16 f16x8;
typedef __attribute__((ext_vector_type(4))) float f32x4;

#define S4 0.35355339059327373f   /* 64^-0.25 */

static __device__ __forceinline__ ushort f2h(float f) {
  return __builtin_bit_cast(ushort, (_Float16)f);
}

static __device__ __forceinline__ void gload16(const void* g, void* l) {
  __builtin_amdgcn_global_load_lds((const __attribute__((address_space(1))) void*)g,
                                   (__attribute__((address_space(3))) void*)l, 16, 0, 0);
}

static __device__ __forceinline__ f16x8 cvt8(float4 a, float4 b) {
  f16x8 h;
  h[0] = (_Float16)a.x; h[1] = (_Float16)a.y; h[2] = (_Float16)a.z; h[3] = (_Float16)a.w;
  h[4] = (_Float16)b.x; h[5] = (_Float16)b.y; h[6] = (_Float16)b.z; h[7] = (_Float16)b.w;
  return h;
}

// ---------------------------------------------------------------------------
// Generic C[M,N] = A[M,K] @ B[N,K]^T (+ epilogue), fp16 MFMA, fp32 accum.
// EPI 3: +bias[col] -> fp32        (out projection)
// EPI 5: raw fp32 store            (ctx split-K partials)
// EPI 6: 0.0625*exp(acc - rv[col]) + 1e-4 -> fp16 (phi K^T, col-diag)
// ZMODE 0/2/3 as before.
// ---------------------------------------------------------------------------
template<int BM, int BN, int WR, int WC, int EPI, int ZMODE>
__global__ __launch_bounds__(256) void gemm_bt(
    const ushort* __restrict__ Ah, const ushort* __restrict__ Bh,
    const float* __restrict__ bias, ushort* __restrict__ Cb,
    float* __restrict__ Cf, const float* __restrict__ rv0,
    int K, int ldA, int ldB, int ldC, int Mz,
    long sAz, long sBz, long sCz)
{
  constexpr int BK = 32;
  constexpr int WTM = BM / WR, WTN = BN / WC;
  constexpr int MI = WTM / 16, NI = WTN / 16;
  constexpr int LDSB = (BM + BN) * 64;

  __shared__ uint4 smem4[LDSB / 16];
  char* smem = (char*)smem4;
  ushort* As = (ushort*)smem;                 // [BM][32]
  ushort* Bs = (ushort*)(smem + BM * 64);     // [BN][32]

  const int tid = threadIdx.x;
  const int l = tid & 63, w = tid >> 6;
  const int wr = w / WC, wc = w % WC;
  const int lr = l & 15, lk = l >> 4;
  const int tm = blockIdx.x * BM, tn = blockIdx.y * BN;
  const int z = blockIdx.z;

  long aoff = 0, boff = 0;
  if (ZMODE == 0) { aoff = (long)z * sAz; boff = (long)z * sBz; }
  if (ZMODE == 2) { aoff = (long)z * sAz; boff = (long)(z >> 3) * sBz + (z & 7) * 64; }
  if (ZMODE == 3) {
    aoff = (long)(z & 15) * sAz + (long)(z >> 4) * 1024;
    boff = (long)(z & 15) * sBz + (long)(z >> 4) * 1024;
  }
  Ah += aoff; Bh += boff;
  const float* rv = (EPI == 6) ? (rv0 + (long)z * Mz) : nullptr;
  const long coff = (long)z * sCz;

  f32x4 acc[MI][NI];
#pragma unroll
  for (int i = 0; i < MI; ++i)
#pragma unroll
    for (int j = 0; j < NI; ++j) acc[i][j] = f32x4{0.f, 0.f, 0.f, 0.f};

  for (int k0 = 0; k0 < K; k0 += BK) {
    constexpr int AB = BM * 64;
#pragma unroll
    for (int s = 0; s < (AB + 4095) / 4096; ++s) {
      const int base = s * 4096 + w * 1024;
      if (base < AB) {
        const int idx = base + l * 16;
        gload16(Ah + (long)(tm + (idx >> 6)) * ldA + k0 + ((idx & 63) >> 1),
                (char*)As + base);
      }
    }
    constexpr int BB = BN * 64;
#pragma unroll
    for (int s = 0; s < (BB + 4095) / 4096; ++s) {
      const int base = s * 4096 + w * 1024;
      if (base < BB) {
        const int idx = base + l * 16;
        gload16(Bh + (long)(tn + (idx >> 6)) * ldB + k0 + ((idx & 63) >> 1),
                (char*)Bs + base);
      }
    }
    __syncthreads();

    f16x8 af[MI], bfr[NI];
#pragma unroll
    for (int mi = 0; mi < MI; ++mi)
      af[mi] = *(const f16x8*)(As + (wr * WTM + mi * 16 + lr) * 32 + lk * 8);
#pragma unroll
    for (int ni = 0; ni < NI; ++ni)
      bfr[ni] = *(const f16x8*)(Bs + (wc * WTN + ni * 16 + lr) * 32 + lk * 8);
#pragma unroll
    for (int mi = 0; mi < MI; ++mi)
#pragma unroll
      for (int ni = 0; ni < NI; ++ni)
        acc[mi][ni] = __builtin_amdgcn_mfma_f32_16x16x32_f16(af[mi], bfr[ni], acc[mi][ni], 0, 0, 0);
    __syncthreads();
  }

#pragma unroll
  for (int mi = 0; mi < MI; ++mi) {
#pragma unroll
    for (int j = 0; j < 4; ++j) {
      const int row = tm + wr * WTM + mi * 16 + lk * 4 + j;
#pragma unroll
      for (int ni = 0; ni < NI; ++ni) {
        const int col = tn + wc * WTN + ni * 16 + lr;
        float v = acc[mi][ni][j];
        if (EPI == 3) v += bias[col];
        if (EPI == 6) v = 0.0625f * __expf(v - rv[col]) + 1e-4f;
        if (EPI == 3 || EPI == 5) {
          Cf[coff + (long)row * ldC + col] = v;
        } else {
          Cb[coff + (long)row * ldC + col] = f2h(v);
        }
      }
    }
  }
}

// ---------------------------------------------------------------------------
// frontend_k: merged Q-proj + K-proj + V^T-proj in ONE launch. grid (128,1,12):
//   z<8:  qkproj path (z&1 = q/k, z>>1 = 128-col block; dbuf fp32 staging)
//   z>=8: vproj path (z-8 = WV row block, bx = v row block; BF32 staging)
// 48 KB LDS -> 3 blocks/CU.
// ---------------------------------------------------------------------------
__global__ __launch_bounds__(256) void frontend_k(
    const float* __restrict__ qf, const float* __restrict__ kf,
    const float* __restrict__ vf,
    const ushort* __restrict__ wqh, const ushort* __restrict__ wkh,
    const ushort* __restrict__ wvh,
    const float* __restrict__ bq, const float* __restrict__ bk,
    const float* __restrict__ bv,
    ushort* __restrict__ Qh, ushort* __restrict__ Kh,
    ushort* __restrict__ Vt,
    float* __restrict__ diagQ, float* __restrict__ diagK)
{
  __shared__ uint4 smem4[3072];   // 49152 B
  char* smem = (char*)smem4;
  const int tid = threadIdx.x;
  const int l = tid & 63, w = tid >> 6;
  const int wr = w >> 1, wc = w & 1;
  const int lr = l & 15, lk = l >> 4;
  const int z = blockIdx.z;

  if (z < 8) {
    const int qk = z & 1;
    const float*  Af   = qk ? kf : qf;
    const ushort* Bh   = qk ? wkh : wqh;
    const float*  bias = qk ? bk : bq;
    ushort*       Cb   = qk ? Kh : Qh;
    float*        dg   = qk ? diagK : diagQ;
    const int tm = blockIdx.x * 128;
    const int tn = (z >> 1) * 128;

    char* AsF[2] = { smem, smem + 16384 };
    char* Bsb[2] = { smem + 32768, smem + 40960 };
    const int baseA = w * 1024;

    f32x4 acc[4][4];
#pragma unroll
    for (int i = 0; i < 4; ++i)
#pragma unroll
      for (int j = 0; j < 4; ++j) acc[i][j] = f32x4{0.f, 0.f, 0.f, 0.f};

#pragma unroll
    for (int s = 0; s < 4; ++s) {
      const int base = s * 4096 + baseA;
      const int D = base + l * 16;
      const int m = D >> 7, pos = (D >> 4) & 7;
      const int g = pos ^ (m & 7);
      gload16(Af + (long)(tm + m) * 512 + g * 4, AsF[0] + base);
    }
#pragma unroll
    for (int s = 0; s < 2; ++s) {
      const int base = s * 4096 + baseA;
      const int D = base + l * 16;
      const int m = D >> 6, pos = (D >> 4) & 3;
      const int g = pos ^ (m & 3);
      gload16(Bh + (long)(tn + m) * 512 + g * 8, Bsb[0] + base);
    }
    __syncthreads();

#pragma unroll
    for (int t = 0; t < 16; ++t) {
      const int cur = t & 1, nxt = cur ^ 1;
      if (t < 15) {
        const int kn = (t + 1) * 32;
#pragma unroll
        for (int s = 0; s < 4; ++s) {
          const int base = s * 4096 + baseA;
          const int D = base + l * 16;
          const int m = D >> 7, pos = (D >> 4) & 7;
          const int g = pos ^ (m & 7);
          gload16(Af + (long)(tm + m) * 512 + kn + g * 4, AsF[nxt] + base);
        }
#pragma unroll
        for (int s = 0; s < 2; ++s) {
          const int base = s * 4096 + baseA;
          const int D = base + l * 16;
          const int m = D >> 6, pos = (D >> 4) & 3;
          const int g = pos ^ (m & 3);
          gload16(Bh + (long)(tn + m) * 512 + kn + g * 8, Bsb[nxt] + base);
        }
      }

      f16x8 af[4], bfr[4];
#pragma unroll
      for (int mi = 0; mi < 4; ++mi) {
        const int row = wr * 64 + mi * 16 + lr;
        const char* rb = AsF[cur] + row * 128;
        float4 f0 = *(const float4*)(rb + ((((lk << 1) | 0) ^ (row & 7)) << 4));
        float4 f1 = *(const float4*)(rb + ((((lk << 1) | 1) ^ (row & 7)) << 4));
        af[mi] = cvt8(f0, f1);
      }
#pragma unroll
      for (int ni = 0; ni < 4; ++ni) {
        const int row = wc * 64 + ni * 16 + lr;
        const int pb = (lk ^ (row & 3)) << 4;
        bfr[ni] = *(const f16x8*)(Bsb[cur] + row * 64 + pb);
      }
#pragma unroll
      for (int mi = 0; mi < 4; ++mi)
#pragma unroll
        for (int ni = 0; ni < 4; ++ni)
          acc[mi][ni] = __builtin_amdgcn_mfma_f32_16x16x32_f16(af[mi], bfr[ni], acc[mi][ni], 0, 0, 0);
      __syncthreads();
    }

#pragma unroll
    for (int mi = 0; mi < 4; ++mi) {
#pragma unroll
      for (int j = 0; j < 4; ++j) {
        const int row = tm + wr * 64 + mi * 16 + lk * 4 + j;
        float ds = 0.f;
#pragma unroll
        for (int ni = 0; ni < 4; ++ni) {
          const int col = tn + wc * 64 + ni * 16 + lr;
          float v = acc[mi][ni][j] + bias[col];
          ds += v * v;
          Cb[(long)row * 512 + col] = f2h(v);
        }
        ds += __shfl_xor(ds, 1, 64);
        ds += __shfl_xor(ds, 2, 64);
        ds += __shfl_xor(ds, 4, 64);
        ds += __shfl_xor(ds, 8, 64);
        if (lr == 0) {
          const int b = row >> 13, nn = row & 8191;
          const int head = (tn + wc * 64) >> 6;
          dg[(long)(b * 8 + head) * 8192 + nn] = 0.0625f * ds;
        }
      }
    }
  } else {
    const int tm = (z - 8) * 128;
    const int tn = blockIdx.x * 128;
    ushort* As = (ushort*)smem;
    char*   Bb = smem + 8192;

    f32x4 acc[4][4];
#pragma unroll
    for (int i = 0; i < 4; ++i)
#pragma unroll
      for (int j = 0; j < 4; ++j) acc[i][j] = f32x4{0.f, 0.f, 0.f, 0.f};

    for (int k0 = 0; k0 < 512; k0 += 32) {
#pragma unroll
      for (int s = 0; s < 2; ++s) {
        const int base = s * 4096 + w * 1024;
        const int idx = base + l * 16;
        gload16(wvh + (long)(tm + (idx >> 6)) * 512 + k0 + ((idx & 63) >> 1),
                (char*)As + base);
      }
#pragma unroll
      for (int s = 0; s < 4; ++s) {
        const int base = s * 4096 + w * 1024;
        const int D = base + l * 16;
        const int m = D >> 7, slot = (D >> 4) & 7;
        const int g = slot ^ (m & 7);
        gload16(vf + (long)(tn + m) * 512 + k0 + g * 4, Bb + base);
      }
      __syncthreads();

      f16x8 af[4], bfr[4];
#pragma unroll
      for (int mi = 0; mi < 4; ++mi)
        af[mi] = *(const f16x8*)(As + (wr * 64 + mi * 16 + lr) * 32 + lk * 8);
#pragma unroll
      for (int ni = 0; ni < 4; ++ni) {
        const int row = wc * 64 + ni * 16 + lr;
        const char* rb = Bb + row * 128;
        float4 f0 = *(const float4*)(rb + ((((lk << 1) | 0) ^ (row & 7)) << 4));
        float4 f1 = *(const float4*)(rb + ((((lk << 1) | 1) ^ (row & 7)) << 4));
        bfr[ni] = cvt8(f0, f1);
      }
#pragma unroll
      for (int mi = 0; mi < 4; ++mi)
#pragma unroll
        for (int ni = 0; ni < 4; ++ni)
          acc[mi][ni] = __builtin_amdgcn_mfma_f32_16x16x32_f16(af[mi], bfr[ni], acc[mi][ni], 0, 0, 0);
      __syncthreads();
    }

#pragma unroll
    for (int mi = 0; mi < 4; ++mi) {
#pragma unroll
      for (int j = 0; j < 4; ++j) {
        const int row = tm + wr * 64 + mi * 16 + lk * 4 + j;
#pragma unroll
        for (int ni = 0; ni < 4; ++ni) {
          const int col = tn + wc * 64 + ni * 16 + lr;
          const float v = acc[mi][ni][j] + bv[row];
          const int b = col >> 13, nn = col & 8191;
          const int h = row >> 6, d = row & 63;
          Vt[(long)(b * 8 + h) * 655360 + (long)d * 8192 + nn] = f2h(v);
        }
      }
    }
  }
}

// ---------------------------------------------------------------------------
// phiattn_k v3: fused phi(Q)+attn(+denom), 64-row blocks, all-LDS operands,
// 79.9 KB LDS -> 2 blocks/CU, 3 barriers. grid (bx<128, bh<16).
// ---------------------------------------------------------------------------
__global__ __launch_bounds__(256) void phiattn_k(
    const ushort* __restrict__ Qh, const ushort* __restrict__ pjh,
    const float* __restrict__ diagQ, const ushort* __restrict__ ctxb,
    ushort* __restrict__ attnR)
{
  const int bx = blockIdx.x, bh = blockIdx.y;
  const int b = bh >> 3, h = bh & 7;
  const int tm = bx * 64;
  const int tid = threadIdx.x, l = tid & 63, w = tid >> 6;
  const int lr = l & 15, lk = l >> 4;

  __shared__ uint4 smem4[4992];   // 79872 B
  char* smem = (char*)smem4;
  ushort* P  = (ushort*)smem;              // [64][264]
  ushort* Pj = (ushort*)(smem + 33792);    // [256][72]
  ushort* As = (ushort*)(smem + 70656);    // [64][72]
  ushort* Cs = (ushort*)(smem + 33792);    // [80][264] (overlays Pj/As)

  const ushort* QB = Qh + (long)b * 4194304 + h * 64;
  const float* rv = diagQ + (long)bh * 8192;

#pragma unroll
  for (int it = 0; it < 8; ++it) {
    const int g = it * 256 + tid;
    const int row = g >> 3, colg = (g & 7) * 8;
    *(uint4*)(Pj + row * 72 + colg) = *(const uint4*)(pjh + row * 64 + colg);
  }
#pragma unroll
  for (int it = 0; it < 2; ++it) {
    const int g = it * 256 + tid;
    const int row = g >> 3, colg = (g & 7) * 8;
    *(uint4*)(As + row * 72 + colg) = *(const uint4*)(QB + (long)(tm + row) * 512 + colg);
  }
  __syncthreads();

  f32x4 a2[16];
#pragma unroll
  for (int i = 0; i < 16; ++i) a2[i] = f32x4{0.f, 0.f, 0.f, 0.f};
  {
    f16x8 af0 = *(const f16x8*)(As + (w * 16 + lr) * 72 + lk * 8);
    f16x8 af1 = *(const f16x8*)(As + (w * 16 + lr) * 72 + 32 + lk * 8);
#pragma unroll
    for (int ni = 0; ni < 16; ++ni) {
      f16x8 b0 = *(const f16x8*)(Pj + (ni * 16 + lr) * 72 + lk * 8);
      f16x8 b1 = *(const f16x8*)(Pj + (ni * 16 + lr) * 72 + 32 + lk * 8);
      a2[ni] = __builtin_amdgcn_mfma_f32_16x16x32_f16(af0, b0, a2[ni], 0, 0, 0);
      a2[ni] = __builtin_amdgcn_mfma_f32_16x16x32_f16(af1, b1, a2[ni], 0, 0, 0);
    }
  }
#pragma unroll
  for (int ni = 0; ni < 16; ++ni)
#pragma unroll
    for (int j = 0; j < 4; ++j) {
      const int row = w * 16 + lk * 4 + j;
      const int col = ni * 16 + lr;
      const float vv = 0.0625f * __expf(a2[ni][j] - rv[tm + row]) + 1e-4f;
      P[row * 264 + col] = f2h(vv);
    }
  __syncthreads();

#pragma unroll
  for (int it = 0; it < 10; ++it) {
    const int g = it * 256 + tid;
    const int row = g >> 5, colg = (g & 31) * 8;
    *(uint4*)(Cs + row * 264 + colg) =
        *(const uint4*)(ctxb + (long)bh * 20480 + row * 256 + colg);
  }
  __syncthreads();

  f32x4 acc[5];
#pragma unroll
  for (int i = 0; i < 5; ++i) acc[i] = f32x4{0.f, 0.f, 0.f, 0.f};

  for (int k0 = 0; k0 < 256; k0 += 32) {
    f16x8 pa = *(const f16x8*)(P + (w * 16 + lr) * 264 + k0 + lk * 8);
#pragma unroll
    for (int ni = 0; ni < 5; ++ni) {
      f16x8 cf = *(const f16x8*)(Cs + (ni * 16 + lr) * 264 + k0 + lk * 8);
      acc[ni] = __builtin_amdgcn_mfma_f32_16x16x32_f16(pa, cf, acc[ni], 0, 0, 0);
    }
  }

  ushort* outb = attnR + (long)bh * 524288;
#pragma unroll
  for (int j = 0; j < 4; ++j) {
    const float dv = __shfl(acc[4][j], (l & 48), 64);
    const int row = tm + w * 16 + lk * 4 + j;
#pragma unroll
    for (int ni = 0; ni < 4; ++ni) {
      const int col = ni * 16 + lr;
      outb[(long)row * 64 + col] = f2h(acc[ni][j] / dv);
    }
  }
}

// fp32->fp16 weight conversions (wq,wk,wv,wo,pj*S4) + Vt pad rows
__global__ __launch_bounds__(256) void cvtall_k(
    const float* __restrict__ wq, const float* __restrict__ wk,
    const float* __restrict__ wv, const float* __restrict__ wo,
    const float* __restrict__ pj,
    ushort* __restrict__ wqh, ushort* __restrict__ wkh,
    ushort* __restrict__ wvh, ushort* __restrict__ woh,
    ushort* __restrict__ pjh, ushort* __restrict__ Vt)
{
  int i = blockIdx.x * 256 + threadIdx.x;
  if (i >= 266240) {
    const int j = i - 266240;
    if (j >= 262144) return;
    const int bh = j >> 14, rem = j & 16383, r = rem >> 10, n8 = rem & 1023;
    const unsigned val = (r == 0) ? 0x3C003C00u : 0u;
    uint4 u; u.x = val; u.y = val; u.z = val; u.w = val;
    *(uint4*)(Vt + (long)bh * 655360 + (long)(64 + r) * 8192 + n8 * 8) = u;
    return;
  }
  const float* in; ushort* out; float scale = 1.f; int idx;
  if (i < 65536)       { in = wq; out = wqh; idx = i; }
  else if (i < 131072) { in = wk; out = wkh; idx = i - 65536; }
  else if (i < 196608) { in = wv; out = wvh; idx = i - 131072; }
  else if (i < 262144) { in = wo; out = woh; idx = i - 196608; }
  else                 { in = pj; out = pjh; idx = i - 262144; scale = S4; }
  float4 f = ((const float4*)in)[idx];
  ushort4 o;
  o.x = f2h(f.x * scale); o.y = f2h(f.y * scale);
  o.z = f2h(f.z * scale); o.w = f2h(f.w * scale);
  ((ushort4*)out)[idx] = o;
}

// reduce 8 ctx split-K partials -> fp16 ctxb[bh][80][256] (row 64 = ksum)
__global__ __launch_bounds__(256) void ctxred_k(const float* __restrict__ cp,
                                                ushort* __restrict__ ctxb) {
  const int idx = blockIdx.x * 256 + threadIdx.x;   // 327680
  const int bh = idx / 20480, rem = idx % 20480;
  float a = 0.f;
#pragma unroll
  for (int kc = 0; kc < 8; ++kc) a += cp[(long)(kc * 16 + bh) * 20480 + rem];
  ctxb[idx] = f2h(a);
}

extern "C" void kernel_launch(void* const* d_in, const int* in_sizes, int n_in,
                              void* d_out, int out_size, void* d_ws, size_t ws_size,
                              hipStream_t stream) {
  (void)in_sizes; (void)n_in; (void)out_size; (void)ws_size;
  const float* q  = (const float*)d_in[0];
  const float* k  = (const float*)d_in[1];
  const float* v  = (const float*)d_in[2];
  const float* wq = (const float*)d_in[3];
  const float* bq = (const float*)d_in[4];
  const float* wk = (const float*)d_in[5];
  const float* bk = (const float*)d_in[6];
  const float* wv = (const float*)d_in[7];
  const float* bv = (const float*)d_in[8];
  const float* wo = (const float*)d_in[9];
  const float* bo = (const float*)d_in[10];
  const float* pj = (const float*)d_in[11];

  char* ws = (char*)d_ws;
  ushort* attnR = (ushort*)(ws + 0);          // [16][8192][64]
  float*  cpart = (float*)(ws + 16777216);    // [128][80][256] fp32
  ushort* wqh   = (ushort*)(ws + 27262976);
  ushort* wkh   = (ushort*)(ws + 27787264);
  ushort* wvh   = (ushort*)(ws + 28311552);
  ushort* woh   = (ushort*)(ws + 28835840);
  ushort* pjh   = (ushort*)(ws + 29360128);
  ushort* Qh    = (ushort*)(ws + 29392896);   // [16384][512]
  ushort* Kh    = (ushort*)(ws + 46170112);   // [16384][512]
  ushort* Vt    = (ushort*)(ws + 62947328);   // [16][80][8192] (row64=1s)
  ushort* KpT   = (ushort*)(ws + 83918848);   // [16][256][8192]
  float*  diagQ = (float*)(ws + 151027712);
  float*  diagK = (float*)(ws + 151552000);
  ushort* ctxb  = (ushort*)(ws + 152076288);  // [16][80][256] (row64=ksum)

  // 1. weight conversions + Vt pad (small, single launch)
  cvtall_k<<<2064, 256, 0, stream>>>(wq, wk, wv, wo, pj, wqh, wkh, wvh, woh, pjh, Vt);

  // 2. merged front end: Q-proj + K-proj + V^T-proj in one launch
  frontend_k<<<dim3(128,1,12), 256, 0, stream>>>(
      q, k, v, wqh, wkh, wvh, bq, bk, bv, Qh, Kh, Vt, diagQ, diagK);

  // 3. phi(K)^T: C[m=256][n=8192] per bh -> KpT (col-diag exp epilogue)
  gemm_bt<128,128,2,2,6,2><<<dim3(2,64,16), 256, 0, stream>>>(
      pjh, Kh, nullptr, KpT, nullptr, diagK, 64, 64, 512, 8192, 8192,
      0L, 4194304L, 2097152L);

  // 4. ctx (+ksum via ones row): C[80][m=256] = Vt @ KpT^T, split-K x8,
  //    BN=64 -> 512 blocks (2/CU)
  gemm_bt<80,64,1,4,5,3><<<dim3(1,4,128), 256, 0, stream>>>(
      Vt, KpT, nullptr, nullptr, cpart, nullptr, 1024, 8192, 8192, 256, 0,
      655360L, 2097152L, 20480L);
  ctxred_k<<<1280, 256, 0, stream>>>(cpart, ctxb);

  // 5. fused phi(Q)+attn(+denom) v3 -> attnR
  phiattn_k<<<dim3(128,16), 256, 0, stream>>>(Qh, pjh, diagQ, ctxb, attnR);

  // 6. output projection (+bias) -> fp32 d_out
  gemm_bt<128,128,2,2,3,0><<<dim3(128,4,1), 256, 0, stream>>>(
      attnR, woh, bo, nullptr, (float*)d_out, nullptr, 512, 512, 512, 512, 0,
      0L, 0L, 0L);
}